// Round 7
// baseline (1062.574 us; speedup 1.0000x reference)
//
#include <hip/hip_runtime.h>
#include <math.h>

// Problem constants
#define CC 62
#define TT 2000
#define BB 256
#define VECN 1953          // C*(C+1)/2
#define HID 64
#define NCLS 3
#define NG 31              // disjoint Jacobi pairs per round
#define NT1 32             // ceil(TT / 64)
#define SLD 64             // S row stride (doubles)
#define LDGF 68            // fp32 G column stride (floats, 272B -> 16B aligned)
#define XBUF 4416          // floats per x-tile buffer (row-phase layout, 4404 used)

// Phase-A row base (floats): row c at 68c + 8*(c>>3). Bank phase of row 8g+r
// is (8g+4r)%32 -> the 4 groups a wave touches per b128 read land on distinct
// phases => conflict-free cross-group; within a group each of the 16 lanes
// reads a distinct 16B chunk => 2/bank (free).
#define RB(c) ((c)*68 + (((c) >> 3) << 3))

typedef const unsigned int __attribute__((address_space(1)))* gbl_u32p;
typedef unsigned int __attribute__((address_space(3)))* lds_u32p;

#define WAITV(n) asm volatile("s_waitcnt vmcnt(" #n ")" ::: "memory")

__device__ __forceinline__ void decodePi(int pi, int& i, int& j)
{
    int ii = 0, rem = pi;
    while (rem >= CC - ii) { rem -= (CC - ii); ++ii; }
    i = ii; j = ii + rem;
}

// round-robin (circle method) pair schedule: 31 disjoint pairs, 61 rounds
__device__ __forceinline__ void pairPQ(int r, int k, int& p, int& q)
{
    if (k == 0) { p = 0; q = 1 + (r + 60) % 61; }
    else {
        p = 1 + (r + k - 1) % 61;
        q = 1 + (r + 60 - k) % 61;
    }
    if (p > q) { int t = p; p = q; q = t; }
}

// ---------------------------------------------------------------------------
// FUSED (round 7): Grammian -> cov -> A=WCW^T+epsI -> one-sided Jacobi ->
// log-map -> triu-vec -> MLP head. ONE dispatch, grid=B, block=576 (9 waves).
//
// Changes vs round 6 (584us measured):
//  1. Jacobi rotation params via HW intrinsics (rcp/sqrt/rsq, 1 instr each)
//     instead of IEEE div/sqrt sequences (~10 instrs each). The round loop is
//     VALU-issue-bound (~55 instr/wave/round measured-consistent); this cuts
//     ~20 of them. (c,s) both derive from tf -> rotations stay orthogonal.
//  2. Two-threshold convergence: APPLY rotations at d^2 > np*nq*1e-12
//     (unchanged), but only FLAG continuation at d^2 > np*nq*1e-9. Tail
//     sweeps polishing below 3e-5 relative disappear (~1-2 sweeps saved).
//  3. Phase A 8x8 register tiles: 36 pairs x 16-lane t-split = 576 exactly.
//     16 b128 reads : 256 FMA (2x better than 4x4). Lane-owned distinct
//     chunks -> no XOR swizzle needed (linear DMA); cross-group conflicts
//     fixed by RB() row-phase offsets. fp32 partials -> fp64 every 4 tiles
//     (<=16 products per partial, same bound as round 6's proven path).
//
// LDS overlays: sA region hosts sX(35328B) -> sS(32768B) -> sGf(16864B);
// sC(15624B) -> sVec. Total ~61.4KB static.
// ---------------------------------------------------------------------------
__global__ __launch_bounds__(576) void fused(
    const float* __restrict__ x, const float* __restrict__ cw,
    const float* __restrict__ pw, const float* __restrict__ pbias,
    const float* __restrict__ hw, const float* __restrict__ hb,
    float* __restrict__ out)
{
    const int b = blockIdx.x, tid = threadIdx.x;
    const int wid = tid >> 6, lane = tid & 63;

    __shared__ __align__(16) double sA[4416];   // 35328 B: sX | sS | sGf
    __shared__ __align__(16) double sC[VECN];   // 15624 B: cov | sVec
    __shared__ double sU[9 * 64];
    __shared__ double sNorm[64];
    __shared__ double sD[64];
    __shared__ double sMean[64];
    __shared__ unsigned short sPair[61 * NG];
    __shared__ int    sFlag;
    __shared__ float  sF[HID];

    float*  sX   = reinterpret_cast<float*>(sA);
    double* sS   = sA;
    float*  sGf  = reinterpret_cast<float*>(sA);   // overlays dead sS
    float*  sVec = reinterpret_cast<float*>(sC);

    // ---------------- Phase A: Grammian (8x8 tiles) ----------------
    const int pr = tid >> 4, myks = tid & 15;      // pair slot 0..35, t-lane
    int gi = 0, gj = 0;
    {
        int g = 0, rem = pr;
        while (rem >= 8 - g) { rem -= (8 - g); ++g; }
        gi = g; gj = g + rem;
    }
    const int a0 = 8 * gi, b0 = 8 * gj;
    const int baseA = RB(a0), baseB = RB(b0);      // (a0+r)>>3 == gi for r<8

    double acc[8][8];
    float  accf[8][8];
#pragma unroll
    for (int r = 0; r < 8; ++r)
#pragma unroll
        for (int s = 0; s < 8; ++s) { acc[r][s] = 0.0; accf[r][s] = 0.0f; }

    // Jacobi pair table (region untouched by phase A LDS)
    for (int e = tid; e < 61 * NG; e += 576) {
        int r = e / NG, k = e - r * NG;
        int p, q; pairPQ(r, k, p, q);
        sPair[e] = (unsigned short)(p | (q << 8));
    }
    // pad rows: 62 = ones (mean trick), 63 = zero; both buffers, once.
    if (tid < 128) {
        int bu = tid >> 6, t = tid & 63;
        sX[bu * XBUF + RB(62) + t] = 1.0f;
        sX[bu * XBUF + RB(63) + t] = 0.0f;
    }
    __syncthreads();

    const float* xb = x + (size_t)b * (CC * TT);

    // DMA one tile: wave w issues rows c = w, w+9, ... (w<8: 7 instrs, w=8: 6).
    // Linear source (coalesced), linear dest at RB(c) (global_load_lds).
    auto issueTile = [&](int buf, int tile) {
        const int t0 = tile * 64;
        for (int c = wid; c < CC; c += 9) {
            if (t0 + lane < TT) {
                const float* gp = xb + (size_t)c * TT + t0 + lane;
                __builtin_amdgcn_global_load_lds(
                    (gbl_u32p)gp, (lds_u32p)&sX[buf * XBUF + RB(c)], 4, 0, 0);
            }
        }
    };

    issueTile(0, 0);
    for (int tile = 0; tile < NT1; ++tile) {
        const int cur = tile & 1;
        __builtin_amdgcn_s_barrier();        // prev compute done: buf cur^1 free
        if (tile + 1 < NT1) {
            issueTile(cur ^ 1, tile + 1);
            if (wid < 8) WAITV(7); else WAITV(6);   // cur-tile loads landed
        } else {
            WAITV(0);
        }
        __builtin_amdgcn_sched_barrier(0);
        __builtin_amdgcn_s_barrier();        // all waves' cur loads visible
        {
            const float* xt = &sX[cur * XBUF];
            const int lim = TT - tile * 64;  // 64 except last tile (16)
            if (4 * myks < lim) {
                float4 af[8], bf[8];
#pragma unroll
                for (int r = 0; r < 8; ++r)
                    af[r] = *reinterpret_cast<const float4*>(
                        &xt[baseA + 68 * r + 4 * myks]);
#pragma unroll
                for (int r = 0; r < 8; ++r)
                    bf[r] = *reinterpret_cast<const float4*>(
                        &xt[baseB + 68 * r + 4 * myks]);
#pragma unroll
                for (int k = 0; k < 4; ++k)
#pragma unroll
                    for (int r = 0; r < 8; ++r)
#pragma unroll
                        for (int s = 0; s < 8; ++s)
                            accf[r][s] += (&af[r].x)[k] * (&bf[s].x)[k];
            }
            if ((tile & 3) == 3) {           // fp64 promotion every 4 tiles
#pragma unroll
                for (int r = 0; r < 8; ++r)
#pragma unroll
                    for (int s = 0; s < 8; ++s) {
                        acc[r][s] += (double)accf[r][s];
                        accf[r][s] = 0.0f;
                    }
            }
        }
    }

    // 16-lane t-split reduce (registers only), then sS overlay of sX
#pragma unroll
    for (int r = 0; r < 8; ++r)
#pragma unroll
        for (int s = 0; s < 8; ++s) {
            double v = acc[r][s];
            v += __shfl_xor(v, 1, 16);
            v += __shfl_xor(v, 2, 16);
            v += __shfl_xor(v, 4, 16);
            v += __shfl_xor(v, 8, 16);
            acc[r][s] = v;
        }
    __syncthreads();                 // all sX reads complete before overlay
    if (myks == 0) {
#pragma unroll
        for (int r = 0; r < 8; ++r)
#pragma unroll
            for (int s = 0; s < 8; ++s) {
                int i = a0 + r, j = b0 + s;
                if (i <= j && j <= 62)
                    sS[i * SLD + j] = acc[r][s];
            }
    }
    __syncthreads();

    // ---------------- Phase B: cov -> A -> Jacobi -> log-map ----------------
    if (tid < CC) sMean[tid] = sS[tid * SLD + 62] / (double)TT;
    __syncthreads();

    // packed cov_x = (S - T m m^T)/(T-1)
    for (int pi = tid; pi < VECN; pi += 576) {
        int i, j; decodePi(pi, i, j);
        sC[pi] = (sS[i * SLD + j] - (double)TT * sMean[i] * sMean[j]) / 1999.0;
    }
    __syncthreads();

    // sS dead -> zero fp32 sGf (overlay)
    for (int e = tid; e < CC * LDGF; e += 576) sGf[e] = 0.0f;
    __syncthreads();

    // A = W C W^T + eps I, chunks of 9 output columns; store fp32
    const int jj = tid >> 6, kk = tid & 63;
    for (int j0 = 0; j0 < CC; j0 += 9) {
        const int j = j0 + jj;
        if (kk < CC && j < CC) {
            const float* wr = cw + j * CC;
            double a = 0.0; int idx = kk;
            for (int l = 0; l < kk; ++l) { a += sC[idx] * (double)wr[l]; idx += 61 - l; }
            for (int l = kk; l < CC; ++l) { a += sC[idx] * (double)wr[l]; idx += 1; }
            sU[jj * 64 + kk] = a;    // u_j[k] = (C w_j)[k]
        }
        __syncthreads();
        const int i = kk;
        if (i < CC && j < CC && i <= j) {
            const float* wi = cw + i * CC;
            double a = (i == j) ? 1e-3 : 0.0;
            for (int l = 0; l < CC; ++l) a += (double)wi[l] * sU[jj * 64 + l];
            sGf[j * LDGF + i] = (float)a;
            sGf[i * LDGF + j] = (float)a;
        }
        __syncthreads();
    }

    // initial column norms n_k = ||g_k||^2 (fp64 accumulate over fp32 G)
    if (tid < CC) {
        const float* col = &sGf[tid * LDGF];
        double n = 0.0;
        for (int i2 = 0; i2 < CC; ++i2) n += (double)col[i2] * (double)col[i2];
        sNorm[tid] = n;
    }
    __syncthreads();

    // one-sided Jacobi: group g (16 lanes) handles pair g each round;
    // lane lt owns rows 4lt..4lt+3 (one float4 per column, b128).
    const int g = tid >> 4, lt = tid & 15;
    const bool actJ = (g < NG);
    const int r0 = 4 * lt;

    for (int sweep = 0; sweep < 20; ++sweep) {
        if (tid == 0) sFlag = 0;
        __syncthreads();
        for (int r = 0; r < 61; ++r) {
            if (actJ) {
                int pq = sPair[r * NG + g];
                int p = pq & 255, q = pq >> 8;
                float4* gp = reinterpret_cast<float4*>(&sGf[p * LDGF + r0]);
                float4* gq = reinterpret_cast<float4*>(&sGf[q * LDGF + r0]);
                float4 P = *gp, Q = *gq;
                float df = P.x * Q.x + P.y * Q.y + P.z * Q.z + P.w * Q.w;
                // 16-lane butterfly entirely on VALU: xor1/xor2 quad_perm;
                // row_half_mirror == xor4 and row_mirror == xor8 once values
                // are quad-/half-uniform. Bitwise-identical d on all lanes.
                { int t2 = __builtin_amdgcn_mov_dpp(__float_as_int(df), 0xB1, 0xF, 0xF, true);
                  df += __int_as_float(t2); }   // lane ^= 1
                { int t2 = __builtin_amdgcn_mov_dpp(__float_as_int(df), 0x4E, 0xF, 0xF, true);
                  df += __int_as_float(t2); }   // lane ^= 2
                { int t2 = __builtin_amdgcn_mov_dpp(__float_as_int(df), 0x141, 0xF, 0xF, true);
                  df += __int_as_float(t2); }   // row_half_mirror -> xor 4
                { int t2 = __builtin_amdgcn_mov_dpp(__float_as_int(df), 0x140, 0xF, 0xF, true);
                  df += __int_as_float(t2); }   // row_mirror -> xor 8
                double d = (double)df;
                double np = sNorm[p], nq = sNorm[q];
                double d2 = d * d, bb = np * nq;
                if (d2 > bb * 1e-12) {
                    // HW-intrinsic rotation params (rcp/sqrt/rsq ~1ulp; c,s
                    // both derive from tf -> rotation orthogonal to ~1e-7)
                    float npf = (float)np, nqf = (float)nq;
                    float thf = (nqf - npf) *
                                __builtin_amdgcn_rcpf(2.0f * df);
                    float a2 = fabsf(thf);
                    float tf = __builtin_amdgcn_rcpf(
                        a2 + __builtin_amdgcn_sqrtf(fmaf(a2, a2, 1.0f)));
                    if (thf < 0.0f) tf = -tf;
                    float cf = __builtin_amdgcn_rsqf(fmaf(tf, tf, 1.0f));
                    float sn = tf * cf;
                    *gp = make_float4(cf * P.x - sn * Q.x, cf * P.y - sn * Q.y,
                                      cf * P.z - sn * Q.z, cf * P.w - sn * Q.w);
                    *gq = make_float4(sn * P.x + cf * Q.x, sn * P.y + cf * Q.y,
                                      sn * P.z + cf * Q.z, sn * P.w + cf * Q.w);
                    if (lt == 0) {
                        double td = (double)tf * d;
                        sNorm[p] = np - td; sNorm[q] = nq + td;
                        if (d2 > bb * 1e-9) sFlag = 1;   // flag threshold only
                    }
                }
            }
            __syncthreads();
        }
        int flag = sFlag;
        __syncthreads();
        if (!flag) break;
    }

    // lam_k^2 = ||g_k||^2 (fp64 from fp32 G); d_k = log(max(lam,1e-6))/lam^2
    if (tid < CC) {
        const float* col = &sGf[tid * LDGF];
        double n = 0.0;
        for (int i5 = 0; i5 < CC; ++i5) n += (double)col[i5] * (double)col[i5];
        double lamv = sqrt(n);
        sD[tid] = log(fmax(lamv, 1e-6)) / n;
    }
    __syncthreads();

    // triu vectorization into LDS (sVec overlays dead sC)
    for (int pi = tid; pi < VECN; pi += 576) {
        int i, j; decodePi(pi, i, j);
        double a = 0.0;
        for (int k2 = 0; k2 < CC; ++k2)
            a += sD[k2] * (double)sGf[k2 * LDGF + i] * (double)sGf[k2 * LDGF + j];
        sVec[pi] = (float)a;
    }
    __syncthreads();

    // ---------------- Phase C: MLP head ----------------
    if (wid < 8) {
        for (int hh = 0; hh < 8; ++hh) {
            const int h = wid * 8 + hh;
            const float* w = pw + (size_t)h * VECN;
            float a = 0.0f;
            for (int k = lane; k < VECN; k += 64) a += sVec[k] * w[k];
            a += __shfl_xor(a, 32); a += __shfl_xor(a, 16); a += __shfl_xor(a, 8);
            a += __shfl_xor(a, 4);  a += __shfl_xor(a, 2);  a += __shfl_xor(a, 1);
            if (lane == 0) sF[h] = fmaxf(a + pbias[h], 0.0f);
        }
    }
    __syncthreads();
    if (tid < NCLS) {
        float o = hb[tid];
        for (int hh = 0; hh < HID; ++hh) o += sF[hh] * hw[tid * HID + hh];
        out[b * NCLS + tid] = o;
    }
}

// ---------------------------------------------------------------------------
extern "C" void kernel_launch(void* const* d_in, const int* in_sizes, int n_in,
                              void* d_out, int out_size, void* d_ws, size_t ws_size,
                              hipStream_t stream)
{
    const float* x  = (const float*)d_in[0];
    const float* cw = (const float*)d_in[1];
    // d_in[2] = conv bias: cancels in covariance, unused
    const float* pw = (const float*)d_in[3];
    const float* pb = (const float*)d_in[4];
    const float* hw = (const float*)d_in[5];
    const float* hb = (const float*)d_in[6];
    float* out = (float*)d_out;

    // single fused dispatch; workspace unused
    fused<<<BB, 576, 0, stream>>>(x, cw, pw, pb, hw, hb, out);
}

// Round 8
// 633.983 us; speedup vs baseline: 1.6760x; 1.6760x over previous
//
#include <hip/hip_runtime.h>
#include <math.h>

// Problem constants
#define CC 62
#define TT 2000
#define BB 256
#define VECN 1953          // C*(C+1)/2
#define HID 64
#define NCLS 3
#define NG 31              // disjoint Jacobi pairs per round
#define LDX 68             // x-tile row stride (floats)
#define XBUF (64 * LDX)    // floats per x-tile buffer (4352)
#define NT1 32             // ceil(TT / 64)
#define SLD 64             // S row stride (doubles)
#define LDGF 68            // fp32 G column stride (floats, 272B -> 16B aligned)

typedef const unsigned int __attribute__((address_space(1)))* gbl_u32p;
typedef unsigned int __attribute__((address_space(3)))* lds_u32p;

#define WAITV(n) asm volatile("s_waitcnt vmcnt(" #n ")" ::: "memory")

__device__ __forceinline__ void decodePi(int pi, int& i, int& j)
{
    int ii = 0, rem = pi;
    while (rem >= CC - ii) { rem -= (CC - ii); ++ii; }
    i = ii; j = ii + rem;
}

// round-robin (circle method) pair schedule: 31 disjoint pairs, 61 rounds
__device__ __forceinline__ void pairPQ(int r, int k, int& p, int& q)
{
    if (k == 0) { p = 0; q = 1 + (r + 60) % 61; }
    else {
        p = 1 + (r + k - 1) % 61;
        q = 1 + (r + 60 - k) % 61;
    }
    if (p > q) { int t = p; p = q; q = t; }
}

// ---------------------------------------------------------------------------
// FUSED (round 8): Grammian -> cov -> A=WCW^T+epsI -> one-sided Jacobi ->
// log-map -> triu-vec -> MLP head. ONE dispatch, grid=B, block=576 (9 waves).
//
// Round-7 post-mortem: 8x8 phase-A tiles demanded ~280 live VGPRs; compiler
// allocated 84 and spilled accumulators to scratch (WRITE_SIZE 10KB->1.06GB,
// dur 584->950us). THIS ROUND: phase A reverted verbatim to the round-6
// 4x4-tile structure (proven 76 VGPR, no spill, 584us total). KEPT from
// round 7 (numerics validated: absmax bit-identical, passed):
//  1. Jacobi rotation params via HW intrinsics (rcp/sqrt/rsq, 1 instr each)
//     instead of IEEE div/sqrt sequences — the round loop is VALU-issue-
//     bound, this cuts ~20 of ~55 instrs/wave/round.
//  2. Two-threshold convergence: APPLY rotations at d^2 > np*nq*1e-12,
//     FLAG continuation only at d^2 > np*nq*1e-9 (saves tail sweeps).
//
// LDS overlays: sA region hosts sX(34816B) -> sS(32768B) -> sGf(16864B);
// sC(15624B) -> sVec. Total ~60.6KB static.
// ---------------------------------------------------------------------------
__global__ __launch_bounds__(576) void fused(
    const float* __restrict__ x, const float* __restrict__ cw,
    const float* __restrict__ pw, const float* __restrict__ pbias,
    const float* __restrict__ hw, const float* __restrict__ hb,
    float* __restrict__ out)
{
    const int b = blockIdx.x, tid = threadIdx.x;
    const int wid = tid >> 6, lane = tid & 63;

    __shared__ __align__(16) double sA[4352];   // 34816 B: sX | sS | sGf
    __shared__ __align__(16) double sC[VECN];   // 15624 B: cov | sVec
    __shared__ double sU[9 * 64];
    __shared__ double sNorm[64];
    __shared__ double sD[64];
    __shared__ double sMean[64];
    __shared__ unsigned short sPair[61 * NG];
    __shared__ int    sFlag;
    __shared__ float  sF[HID];

    float*  sX   = reinterpret_cast<float*>(sA);
    double* sS   = sA;
    float*  sGf  = reinterpret_cast<float*>(sA);   // overlays dead sS
    float*  sVec = reinterpret_cast<float*>(sC);

    // ---------------- Phase A: Grammian (round-6 proven 4x4) ----------------
    const int slot = tid >> 2, myks = tid & 3;
    const bool actA = (slot < 136);
    int gi = 0, gj = 0;
    if (actA) {
        int g = 0, rem = slot;
        while (rem >= 16 - g) { rem -= (16 - g); ++g; }
        gi = g; gj = g + rem;
    }
    const int a0 = 4 * gi, b0 = 4 * gj;
    const int pA = gi >> 1, pB = gj >> 1;   // (4g+r)>>3 for r<4

    double acc[4][4];
    float  accf[4][4];
#pragma unroll
    for (int r = 0; r < 4; ++r)
#pragma unroll
        for (int c = 0; c < 4; ++c) { acc[r][c] = 0.0; accf[r][c] = 0.0f; }

    // Jacobi pair table (region untouched by phase A LDS)
    for (int e = tid; e < 61 * NG; e += 576) {
        int r = e / NG, k = e - r * NG;
        int p, q; pairPQ(r, k, p, q);
        sPair[e] = (unsigned short)(p | (q << 8));
    }
    // pad rows: 62 = ones (mean trick), 63 = zero; both buffers, once.
    if (tid < 128) {
        int bu = tid >> 6, t = tid & 63;
        sX[bu * XBUF + 62 * LDX + t] = 1.0f;
        sX[bu * XBUF + 63 * LDX + t] = 0.0f;
    }
    __syncthreads();

    const float* xb = x + (size_t)b * (CC * TT);

    // DMA one tile: wave w issues rows c = w, w+9, ... (w<8: 7 rows, w=8: 6).
    // Global source chunk-XOR pre-swizzled (p(c)=c>>3); LDS dest linear
    // (global_load_lds constraint). LDS chunk c' of row c holds global chunk
    // c'^p(c), so compute reads chunk m^p(row) to get global chunk m.
    auto issueTile = [&](int buf, int tile) {
        const int t0 = tile * 64;
        for (int c = wid; c < CC; c += 9) {
            const int ps = c >> 3;
            const int tt = 4 * ((lane >> 2) ^ ps) + (lane & 3);
            if (t0 + tt < TT) {
                const float* gp = xb + (size_t)c * TT + t0 + tt;
                __builtin_amdgcn_global_load_lds(
                    (gbl_u32p)gp, (lds_u32p)&sX[buf * XBUF + c * LDX], 4, 0, 0);
            }
        }
    };

    issueTile(0, 0);
    for (int tile = 0; tile < NT1; ++tile) {
        const int cur = tile & 1;
        __builtin_amdgcn_s_barrier();        // prev compute done: buf cur^1 free
        if (tile + 1 < NT1) {
            issueTile(cur ^ 1, tile + 1);
            if (wid < 8) WAITV(7); else WAITV(6);   // cur-tile loads landed
        } else {
            WAITV(0);
        }
        __builtin_amdgcn_sched_barrier(0);
        __builtin_amdgcn_s_barrier();        // all waves' cur loads visible
        if (actA) {
            const float* xt = &sX[cur * XBUF];
            const int nq = min(16, (TT - tile * 64) >> 2);
            for (int m = myks; m < nq; m += 4) {
                const int ca = 4 * (m ^ pA), cb = 4 * (m ^ pB);
                float4 af[4], bf[4];
#pragma unroll
                for (int r = 0; r < 4; ++r)
                    af[r] = *reinterpret_cast<const float4*>(&xt[(a0 + r) * LDX + ca]);
#pragma unroll
                for (int r = 0; r < 4; ++r)
                    bf[r] = *reinterpret_cast<const float4*>(&xt[(b0 + r) * LDX + cb]);
#pragma unroll
                for (int k = 0; k < 4; ++k) {
#pragma unroll
                    for (int r = 0; r < 4; ++r)
#pragma unroll
                        for (int s = 0; s < 4; ++s)
                            accf[r][s] += (&af[r].x)[k] * (&bf[s].x)[k];
                }
            }
            // per-tile fp64 promotion (<=16 fp32 products per partial)
#pragma unroll
            for (int r = 0; r < 4; ++r)
#pragma unroll
                for (int c = 0; c < 4; ++c) {
                    acc[r][c] += (double)accf[r][c];
                    accf[r][c] = 0.0f;
                }
        }
    }

    // 4-lane t-split reduce (registers only), then sS overlay of sX
#pragma unroll
    for (int r = 0; r < 4; ++r)
#pragma unroll
        for (int c = 0; c < 4; ++c) {
            double v = acc[r][c];
            v += __shfl_xor(v, 1, 4);
            v += __shfl_xor(v, 2, 4);
            acc[r][c] = v;
        }
    __syncthreads();                 // all sX reads complete before overlay
    if (actA && myks == 0) {
#pragma unroll
        for (int r = 0; r < 4; ++r)
#pragma unroll
            for (int c = 0; c < 4; ++c)
                sS[(a0 + r) * SLD + (b0 + c)] = acc[r][c];
    }
    __syncthreads();

    // ---------------- Phase B: cov -> A -> Jacobi -> log-map ----------------
    if (tid < CC) sMean[tid] = sS[tid * SLD + 62] / (double)TT;
    __syncthreads();

    // packed cov_x = (S - T m m^T)/(T-1)
    for (int pi = tid; pi < VECN; pi += 576) {
        int i, j; decodePi(pi, i, j);
        sC[pi] = (sS[i * SLD + j] - (double)TT * sMean[i] * sMean[j]) / 1999.0;
    }
    __syncthreads();

    // sS dead -> zero fp32 sGf (overlay)
    for (int e = tid; e < CC * LDGF; e += 576) sGf[e] = 0.0f;
    __syncthreads();

    // A = W C W^T + eps I, chunks of 9 output columns; store fp32
    const int jj = tid >> 6, kk = tid & 63;
    for (int j0 = 0; j0 < CC; j0 += 9) {
        const int j = j0 + jj;
        if (kk < CC && j < CC) {
            const float* wr = cw + j * CC;
            double a = 0.0; int idx = kk;
            for (int l = 0; l < kk; ++l) { a += sC[idx] * (double)wr[l]; idx += 61 - l; }
            for (int l = kk; l < CC; ++l) { a += sC[idx] * (double)wr[l]; idx += 1; }
            sU[jj * 64 + kk] = a;    // u_j[k] = (C w_j)[k]
        }
        __syncthreads();
        const int i = kk;
        if (i < CC && j < CC && i <= j) {
            const float* wi = cw + i * CC;
            double a = (i == j) ? 1e-3 : 0.0;
            for (int l = 0; l < CC; ++l) a += (double)wi[l] * sU[jj * 64 + l];
            sGf[j * LDGF + i] = (float)a;
            sGf[i * LDGF + j] = (float)a;
        }
        __syncthreads();
    }

    // initial column norms n_k = ||g_k||^2 (fp64 accumulate over fp32 G)
    if (tid < CC) {
        const float* col = &sGf[tid * LDGF];
        double n = 0.0;
        for (int i2 = 0; i2 < CC; ++i2) n += (double)col[i2] * (double)col[i2];
        sNorm[tid] = n;
    }
    __syncthreads();

    // one-sided Jacobi: group g (16 lanes) handles pair g each round;
    // lane lt owns rows 4lt..4lt+3 (one float4 per column, b128).
    const int g = tid >> 4, lt = tid & 15;
    const bool actJ = (g < NG);
    const int r0 = 4 * lt;

    for (int sweep = 0; sweep < 20; ++sweep) {
        if (tid == 0) sFlag = 0;
        __syncthreads();
        for (int r = 0; r < 61; ++r) {
            if (actJ) {
                int pq = sPair[r * NG + g];
                int p = pq & 255, q = pq >> 8;
                float4* gp = reinterpret_cast<float4*>(&sGf[p * LDGF + r0]);
                float4* gq = reinterpret_cast<float4*>(&sGf[q * LDGF + r0]);
                float4 P = *gp, Q = *gq;
                float df = P.x * Q.x + P.y * Q.y + P.z * Q.z + P.w * Q.w;
                // 16-lane butterfly entirely on VALU: xor1/xor2 quad_perm;
                // row_half_mirror == xor4 and row_mirror == xor8 once values
                // are quad-/half-uniform. Bitwise-identical d on all lanes.
                { int t2 = __builtin_amdgcn_mov_dpp(__float_as_int(df), 0xB1, 0xF, 0xF, true);
                  df += __int_as_float(t2); }   // lane ^= 1
                { int t2 = __builtin_amdgcn_mov_dpp(__float_as_int(df), 0x4E, 0xF, 0xF, true);
                  df += __int_as_float(t2); }   // lane ^= 2
                { int t2 = __builtin_amdgcn_mov_dpp(__float_as_int(df), 0x141, 0xF, 0xF, true);
                  df += __int_as_float(t2); }   // row_half_mirror -> xor 4
                { int t2 = __builtin_amdgcn_mov_dpp(__float_as_int(df), 0x140, 0xF, 0xF, true);
                  df += __int_as_float(t2); }   // row_mirror -> xor 8
                double d = (double)df;
                double np = sNorm[p], nq = sNorm[q];
                double d2 = d * d, bb = np * nq;
                if (d2 > bb * 1e-12) {
                    // HW-intrinsic rotation params (rcp/sqrt/rsq ~1ulp; c,s
                    // both derive from tf -> rotation orthogonal to ~1e-7)
                    float npf = (float)np, nqf = (float)nq;
                    float thf = (nqf - npf) *
                                __builtin_amdgcn_rcpf(2.0f * df);
                    float a2 = fabsf(thf);
                    float tf = __builtin_amdgcn_rcpf(
                        a2 + __builtin_amdgcn_sqrtf(fmaf(a2, a2, 1.0f)));
                    if (thf < 0.0f) tf = -tf;
                    float cf = __builtin_amdgcn_rsqf(fmaf(tf, tf, 1.0f));
                    float sn = tf * cf;
                    *gp = make_float4(cf * P.x - sn * Q.x, cf * P.y - sn * Q.y,
                                      cf * P.z - sn * Q.z, cf * P.w - sn * Q.w);
                    *gq = make_float4(sn * P.x + cf * Q.x, sn * P.y + cf * Q.y,
                                      sn * P.z + cf * Q.z, sn * P.w + cf * Q.w);
                    if (lt == 0) {
                        double td = (double)tf * d;
                        sNorm[p] = np - td; sNorm[q] = nq + td;
                        if (d2 > bb * 1e-9) sFlag = 1;   // flag threshold only
                    }
                }
            }
            __syncthreads();
        }
        int flag = sFlag;
        __syncthreads();
        if (!flag) break;
    }

    // lam_k^2 = ||g_k||^2 (fp64 from fp32 G); d_k = log(max(lam,1e-6))/lam^2
    if (tid < CC) {
        const float* col = &sGf[tid * LDGF];
        double n = 0.0;
        for (int i5 = 0; i5 < CC; ++i5) n += (double)col[i5] * (double)col[i5];
        double lamv = sqrt(n);
        sD[tid] = log(fmax(lamv, 1e-6)) / n;
    }
    __syncthreads();

    // triu vectorization into LDS (sVec overlays dead sC)
    for (int pi = tid; pi < VECN; pi += 576) {
        int i, j; decodePi(pi, i, j);
        double a = 0.0;
        for (int k2 = 0; k2 < CC; ++k2)
            a += sD[k2] * (double)sGf[k2 * LDGF + i] * (double)sGf[k2 * LDGF + j];
        sVec[pi] = (float)a;
    }
    __syncthreads();

    // ---------------- Phase C: MLP head ----------------
    if (wid < 8) {
        for (int hh = 0; hh < 8; ++hh) {
            const int h = wid * 8 + hh;
            const float* w = pw + (size_t)h * VECN;
            float a = 0.0f;
            for (int k = lane; k < VECN; k += 64) a += sVec[k] * w[k];
            a += __shfl_xor(a, 32); a += __shfl_xor(a, 16); a += __shfl_xor(a, 8);
            a += __shfl_xor(a, 4);  a += __shfl_xor(a, 2);  a += __shfl_xor(a, 1);
            if (lane == 0) sF[h] = fmaxf(a + pbias[h], 0.0f);
        }
    }
    __syncthreads();
    if (tid < NCLS) {
        float o = hb[tid];
        for (int hh = 0; hh < HID; ++hh) o += sF[hh] * hw[tid * HID + hh];
        out[b * NCLS + tid] = o;
    }
}

// ---------------------------------------------------------------------------
extern "C" void kernel_launch(void* const* d_in, const int* in_sizes, int n_in,
                              void* d_out, int out_size, void* d_ws, size_t ws_size,
                              hipStream_t stream)
{
    const float* x  = (const float*)d_in[0];
    const float* cw = (const float*)d_in[1];
    // d_in[2] = conv bias: cancels in covariance, unused
    const float* pw = (const float*)d_in[3];
    const float* pb = (const float*)d_in[4];
    const float* hw = (const float*)d_in[5];
    const float* hb = (const float*)d_in[6];
    float* out = (float*)d_out;

    // single fused dispatch; workspace unused
    fused<<<BB, 576, 0, stream>>>(x, cw, pw, pb, hw, hb, out);
}